// Round 1
// baseline (1857.099 us; speedup 1.0000x reference)
//
#include <hip/hip_runtime.h>
#include <hip/hip_bf16.h>

#define NF 128
#define EF 32
#define CF 3
#define H  512

__device__ __forceinline__ float celu_f(float x) {
    return x > 0.0f ? x : expm1f(x);
}

// Kernel 1: h = celu(hfeats@Wn+bn) -> ws.h ; c512 = celu(cfeats@Wc+bc) (LDS only);
//           c_out = cfeats + celu(c512@Wco+bco)
__global__ void node_expand_kernel(const float* __restrict__ hfeats,
                                   const float* __restrict__ cfeats,
                                   const float* __restrict__ Wn, const float* __restrict__ bn,
                                   const float* __restrict__ Wc, const float* __restrict__ bc,
                                   const float* __restrict__ Wco, const float* __restrict__ bco,
                                   float* __restrict__ h,
                                   float* __restrict__ c_out, int n_nodes) {
    __shared__ float hf[16][NF];       // 8 KB
    __shared__ float cf[16][4];
    __shared__ float c512[16][H + 4];  // ~33 KB (pad 4 to break bank conflicts in c_out phase)
    const int t = threadIdx.x;
    const int node0 = blockIdx.x * 16;

    for (int i = t; i < 16 * NF; i += 256) {
        int n = i / NF, k = i % NF;
        int node = node0 + n;
        hf[n][k] = (node < n_nodes) ? hfeats[(size_t)node * NF + k] : 0.0f;
    }
    for (int i = t; i < 16 * CF; i += 256) {
        int n = i / CF, k = i % CF;
        int node = node0 + n;
        cf[n][k] = (node < n_nodes) ? cfeats[(size_t)node * CF + k] : 0.0f;
    }
    __syncthreads();

    for (int jj = 0; jj < 2; ++jj) {
        const int j = jj * 256 + t;
        float acc[16];
        const float bj = bn[j];
        #pragma unroll
        for (int n = 0; n < 16; ++n) acc[n] = bj;
        for (int kt = 0; kt < NF / 8; ++kt) {
            float w[8];
            #pragma unroll
            for (int u = 0; u < 8; ++u) w[u] = Wn[(size_t)(kt * 8 + u) * H + j];
            #pragma unroll
            for (int n = 0; n < 16; ++n) {
                float a = 0.0f;
                #pragma unroll
                for (int u = 0; u < 8; ++u) a += hf[n][kt * 8 + u] * w[u];
                acc[n] += a;
            }
        }
        const float w0 = Wc[j], w1 = Wc[H + j], w2 = Wc[2 * H + j];
        const float bcj = bc[j];
        #pragma unroll
        for (int n = 0; n < 16; ++n) {
            int node = node0 + n;
            float cv = celu_f(bcj + cf[n][0] * w0 + cf[n][1] * w1 + cf[n][2] * w2);
            c512[n][j] = cv;
            if (node < n_nodes) {
                h[(size_t)node * H + j] = celu_f(acc[n]);
            }
        }
    }
    __syncthreads();

    // c_out: 16 nodes x 3 outputs
    if (t < 16 * CF) {
        int n = t / CF, o = t % CF;
        int node = node0 + n;
        if (node < n_nodes) {
            float s = bco[o];
            for (int j2 = 0; j2 < H; ++j2) s += c512[n][j2] * Wco[j2 * CF + o];
            c_out[(size_t)node * CF + o] = cfeats[(size_t)node * CF + o] + celu_f(s);
        }
    }
}

// Kernel 2 (edge): e512 = celu(efeats@We+be) in LDS;
//   x = |c_d - c_s| * (h_s * e512) with c recomputed from cfeats (3 MACs);
//   atomicAdd into k[dst]; e_out = efeats + celu(e512@Weo+beo)
__global__ void edge_kernel(const float* __restrict__ efeats,
                            const int* __restrict__ src, const int* __restrict__ dst,
                            const float* __restrict__ cfeats,
                            const float* __restrict__ We, const float* __restrict__ be,
                            const float* __restrict__ Weo, const float* __restrict__ beo,
                            const float* __restrict__ Wc, const float* __restrict__ bc,
                            const float* __restrict__ h,
                            float* __restrict__ k_acc, float* __restrict__ e_out,
                            int n_edges) {
    __shared__ float ef[16][EF];       // 2 KB
    __shared__ float e512[16][H + 4];  // ~33 KB
    __shared__ int s_src[16], s_dst[16];
    __shared__ float cfs[16][4], cfd[16][4];
    const int t = threadIdx.x;
    const int e0 = blockIdx.x * 16;

    for (int i = t; i < 16 * EF; i += 256) {
        int n = i / EF, k = i % EF;
        int e = e0 + n;
        ef[n][k] = (e < n_edges) ? efeats[(size_t)e * EF + k] : 0.0f;
    }
    if (t < 16) {
        int e = e0 + t;
        s_src[t] = (e < n_edges) ? src[e] : 0;
        s_dst[t] = (e < n_edges) ? dst[e] : 0;
    }
    __syncthreads();

    // load cfeats rows for src/dst (needs s_src/s_dst -> after sync)
    if (t < 48) {
        int n = t / CF, k = t % CF;
        cfs[n][k] = cfeats[(size_t)s_src[n] * CF + k];
    } else if (t < 96) {
        int t2 = t - 48;
        int n = t2 / CF, k = t2 % CF;
        cfd[n][k] = cfeats[(size_t)s_dst[n] * CF + k];
    }

    // phase A: e512 = celu(ef @ We + be)
    for (int jj = 0; jj < 2; ++jj) {
        const int j = jj * 256 + t;
        float acc[16];
        const float bj = be[j];
        #pragma unroll
        for (int n = 0; n < 16; ++n) acc[n] = bj;
        #pragma unroll 4
        for (int k = 0; k < EF; ++k) {
            float w = We[(size_t)k * H + j];
            #pragma unroll
            for (int n = 0; n < 16; ++n) acc[n] += ef[n][k] * w;
        }
        #pragma unroll
        for (int n = 0; n < 16; ++n) e512[n][j] = celu_f(acc[n]);
    }
    __syncthreads();

    // phase B: message + atomic scatter
    for (int jj = 0; jj < 2; ++jj) {
        const int j = jj * 256 + t;
        const float w0 = Wc[j], w1 = Wc[H + j], w2 = Wc[2 * H + j];
        const float bcj = bc[j];
        for (int n = 0; n < 16; ++n) {
            int e = e0 + n;
            if (e >= n_edges) continue;
            int s_ = s_src[n], d_ = s_dst[n];
            float cs = celu_f(bcj + cfs[n][0] * w0 + cfs[n][1] * w1 + cfs[n][2] * w2);
            float cd = celu_f(bcj + cfd[n][0] * w0 + cfd[n][1] * w1 + cfd[n][2] * w2);
            float hs = h[(size_t)s_ * H + j];
            float x = fabsf(cd - cs) * (hs * e512[n][j]);
            atomicAdd(&k_acc[(size_t)d_ * H + j], x);
        }
    }

    // phase C: e_out = efeats + celu(e512 @ Weo + beo)  (e512 read-only, no sync needed)
    #pragma unroll
    for (int p = 0; p < 2; ++p) {
        int idx = p * 256 + t;
        int n = idx / EF;   // 0..15
        int o = idx % EF;
        int e = e0 + n;
        if (e < n_edges) {
            float acc = beo[o];
            #pragma unroll 8
            for (int j2 = 0; j2 < H; ++j2) acc += e512[n][j2] * Weo[(size_t)j2 * EF + o];
            e_out[(size_t)e * EF + o] = efeats[(size_t)e * EF + o] + celu_f(acc);
        }
    }
}

// Kernel 3: h_out = hfeats + celu(celu(k@Wn1+bn1)@Wn2+bn2), 8 nodes per block
__global__ void node_out_kernel(const float* __restrict__ hfeats,
                                const float* __restrict__ k_acc,
                                const float* __restrict__ Wn1, const float* __restrict__ bn1,
                                const float* __restrict__ Wn2, const float* __restrict__ bn2,
                                float* __restrict__ h_out, int n_nodes) {
    __shared__ float kl[8][H];   // 16 KB
    __shared__ float tl[8][H];   // 16 KB
    const int t = threadIdx.x;
    const int node0 = blockIdx.x * 8;

    for (int i = t; i < 8 * H; i += 256) {
        int n = i / H, j = i % H;
        int node = node0 + n;
        kl[n][j] = (node < n_nodes) ? k_acc[(size_t)node * H + j] : 0.0f;
    }
    __syncthreads();

    for (int jj = 0; jj < 2; ++jj) {
        const int j = jj * 256 + t;
        float acc[8];
        const float bj = bn1[j];
        #pragma unroll
        for (int n = 0; n < 8; ++n) acc[n] = bj;
        for (int kt = 0; kt < H / 8; ++kt) {
            float w[8];
            #pragma unroll
            for (int u = 0; u < 8; ++u) w[u] = Wn1[(size_t)(kt * 8 + u) * H + j];
            #pragma unroll
            for (int n = 0; n < 8; ++n) {
                float a = 0.0f;
                #pragma unroll
                for (int u = 0; u < 8; ++u) a += kl[n][kt * 8 + u] * w[u];
                acc[n] += a;
            }
        }
        #pragma unroll
        for (int n = 0; n < 8; ++n) tl[n][j] = celu_f(acc[n]);
    }
    __syncthreads();

    // stage 2: 8 nodes x 128 outputs; thread t handles j = t%128, nodes nb+2p
    {
        const int j = t % NF;
        const int nb = t / NF;  // 0 or 1
        float acc2[4];
        const float bj = bn2[j];
        #pragma unroll
        for (int p = 0; p < 4; ++p) acc2[p] = bj;
        for (int kt = 0; kt < H / 8; ++kt) {
            float w[8];
            #pragma unroll
            for (int u = 0; u < 8; ++u) w[u] = Wn2[(size_t)(kt * 8 + u) * NF + j];
            #pragma unroll
            for (int p = 0; p < 4; ++p) {
                const int n = nb + 2 * p;
                float a = 0.0f;
                #pragma unroll
                for (int u = 0; u < 8; ++u) a += tl[n][kt * 8 + u] * w[u];
                acc2[p] += a;
            }
        }
        #pragma unroll
        for (int p = 0; p < 4; ++p) {
            const int n = nb + 2 * p;
            const int node = node0 + n;
            if (node < n_nodes) {
                h_out[(size_t)node * NF + j] =
                    hfeats[(size_t)node * NF + j] + celu_f(acc2[p]);
            }
        }
    }
}

extern "C" void kernel_launch(void* const* d_in, const int* in_sizes, int n_in,
                              void* d_out, int out_size, void* d_ws, size_t ws_size,
                              hipStream_t stream) {
    const float* hfeats = (const float*)d_in[0];
    const float* cfeats = (const float*)d_in[1];
    const float* efeats = (const float*)d_in[2];
    const int*   src    = (const int*)d_in[3];
    const int*   dst    = (const int*)d_in[4];
    const float* Wn  = (const float*)d_in[5];  const float* bn  = (const float*)d_in[6];
    const float* We  = (const float*)d_in[7];  const float* be  = (const float*)d_in[8];
    const float* Wc  = (const float*)d_in[9];  const float* bc  = (const float*)d_in[10];
    const float* Wn1 = (const float*)d_in[11]; const float* bn1 = (const float*)d_in[12];
    const float* Wn2 = (const float*)d_in[13]; const float* bn2 = (const float*)d_in[14];
    const float* Weo = (const float*)d_in[15]; const float* beo = (const float*)d_in[16];
    const float* Wco = (const float*)d_in[17]; const float* bco = (const float*)d_in[18];

    const int n_nodes = in_sizes[0] / NF;
    const int n_edges = in_sizes[2] / EF;

    float* h_buf = (float*)d_ws;                        // [N, H]
    float* k_buf = h_buf + (size_t)n_nodes * H;         // [N, H]

    float* h_out = (float*)d_out;
    float* c_out = h_out + (size_t)n_nodes * NF;
    float* e_out = c_out + (size_t)n_nodes * CF;

    hipMemsetAsync(k_buf, 0, (size_t)n_nodes * H * sizeof(float), stream);

    node_expand_kernel<<<(n_nodes + 15) / 16, 256, 0, stream>>>(
        hfeats, cfeats, Wn, bn, Wc, bc, Wco, bco, h_buf, c_out, n_nodes);

    edge_kernel<<<(n_edges + 15) / 16, 256, 0, stream>>>(
        efeats, src, dst, cfeats, We, be, Weo, beo, Wc, bc,
        h_buf, k_buf, e_out, n_edges);

    node_out_kernel<<<(n_nodes + 7) / 8, 256, 0, stream>>>(
        hfeats, k_buf, Wn1, bn1, Wn2, bn2, h_out, n_nodes);
}

// Round 2
// 1526.108 us; speedup vs baseline: 1.2169x; 1.2169x over previous
//
#include <hip/hip_runtime.h>
#include <hip/hip_bf16.h>

#define NF 128
#define EF 32
#define CF 3
#define H  512

typedef __attribute__((ext_vector_type(8))) short bf16x8;
typedef __attribute__((ext_vector_type(4))) float f32x4;

__device__ __forceinline__ float celu_f(float x) {
    return x > 0.0f ? x : expm1f(x);
}
__device__ __forceinline__ ushort f2b(float f) {
    union { float f; uint u; } v; v.f = f;
    uint u = v.u + 0x7FFF + ((v.u >> 16) & 1);   // RNE
    return (ushort)(u >> 16);
}
__device__ __forceinline__ float b2f(ushort s) {
    union { uint u; float f; } v; v.u = ((uint)s) << 16; return v.f;
}

// prep: Wet[j*EF+k] = bf16(We[k*H+j]);  Weot[o*H+j] = bf16(Weo[j*EF+o])
__global__ void prep_kernel(const float* __restrict__ We, const float* __restrict__ Weo,
                            ushort* __restrict__ Wet, ushort* __restrict__ Weot) {
    int i = blockIdx.x * 256 + threadIdx.x;
    if (i < H * EF) {
        int j = i / EF, k = i % EF;
        Wet[i] = f2b(We[(size_t)k * H + j]);
        int o = i / H, j2 = i % H;
        Weot[i] = f2b(Weo[(size_t)j2 * EF + o]);
    }
}

// Kernel 1: hb = bf16(celu(hfeats@Wn+bn)); cb = bf16(celu(cfeats@Wc+bc));
//           c_out = cfeats + celu(c512@Wco+bco)
__global__ void node_expand_kernel(const float* __restrict__ hfeats,
                                   const float* __restrict__ cfeats,
                                   const float* __restrict__ Wn, const float* __restrict__ bn,
                                   const float* __restrict__ Wc, const float* __restrict__ bc,
                                   const float* __restrict__ Wco, const float* __restrict__ bco,
                                   ushort* __restrict__ hb, ushort* __restrict__ cb,
                                   float* __restrict__ c_out, int n_nodes) {
    __shared__ float hf[16][NF];
    __shared__ float cf[16][4];
    __shared__ float c512[16][H + 4];
    const int t = threadIdx.x;
    const int node0 = blockIdx.x * 16;

    for (int i = t; i < 16 * NF; i += 256) {
        int n = i / NF, k = i % NF;
        int node = node0 + n;
        hf[n][k] = (node < n_nodes) ? hfeats[(size_t)node * NF + k] : 0.0f;
    }
    for (int i = t; i < 16 * CF; i += 256) {
        int n = i / CF, k = i % CF;
        int node = node0 + n;
        cf[n][k] = (node < n_nodes) ? cfeats[(size_t)node * CF + k] : 0.0f;
    }
    __syncthreads();

    for (int jj = 0; jj < 2; ++jj) {
        const int j = jj * 256 + t;
        float acc[16];
        const float bj = bn[j];
        #pragma unroll
        for (int n = 0; n < 16; ++n) acc[n] = bj;
        for (int kt = 0; kt < NF / 8; ++kt) {
            float w[8];
            #pragma unroll
            for (int u = 0; u < 8; ++u) w[u] = Wn[(size_t)(kt * 8 + u) * H + j];
            #pragma unroll
            for (int n = 0; n < 16; ++n) {
                float a = 0.0f;
                #pragma unroll
                for (int u = 0; u < 8; ++u) a += hf[n][kt * 8 + u] * w[u];
                acc[n] += a;
            }
        }
        const float w0 = Wc[j], w1 = Wc[H + j], w2 = Wc[2 * H + j];
        const float bcj = bc[j];
        #pragma unroll
        for (int n = 0; n < 16; ++n) {
            int node = node0 + n;
            float cv = celu_f(bcj + cf[n][0] * w0 + cf[n][1] * w1 + cf[n][2] * w2);
            c512[n][j] = cv;
            if (node < n_nodes) {
                hb[(size_t)node * H + j] = f2b(celu_f(acc[n]));
                cb[(size_t)node * H + j] = f2b(cv);
            }
        }
    }
    __syncthreads();

    if (t < 16 * CF) {
        int n = t / CF, o = t % CF;
        int node = node0 + n;
        if (node < n_nodes) {
            float s = bco[o];
            for (int j2 = 0; j2 < H; ++j2) s += c512[n][j2] * Wco[j2 * CF + o];
            c_out[(size_t)node * CF + o] = cfeats[(size_t)node * CF + o] + celu_f(s);
        }
    }
}

// Kernel 2 (edge, MFMA): 32 edges/block, 4 waves.
// Phase A: e512 = celu(ef@We+be) via mfma 16x16x32 -> swizzled LDS (bf16)
// Phase B: x = |c_d-c_s|*(h_s*e512), atomicAdd to k
// Phase C: e_out = efeats + celu(e512@Weo+beo) via mfma
__global__ __launch_bounds__(256) void edge_kernel(
        const float* __restrict__ efeats,
        const int* __restrict__ src, const int* __restrict__ dst,
        const ushort* __restrict__ Wet, const float* __restrict__ be,
        const ushort* __restrict__ Weot, const float* __restrict__ beo,
        const ushort* __restrict__ hb, const ushort* __restrict__ cb,
        float* __restrict__ k_acc, float* __restrict__ e_out, int n_edges) {
    __shared__ ushort e512[32 * 512];      // 32 KB, XOR-swizzled in 8-elem groups
    __shared__ int s_src[32], s_dst[32];
    const int t = threadIdx.x;
    const int lane = t & 63;
    const int w = t >> 6;
    const int e0 = blockIdx.x * 32;

    if (t < 32) {
        int e = e0 + t;
        s_src[t] = (e < n_edges) ? src[e] : 0;
        s_dst[t] = (e < n_edges) ? dst[e] : 0;
    }

    const int ar = lane & 15;          // row/col within 16-tile
    const int ak = (lane >> 4) * 8;    // k-start for A/B fragments

    // ---- Phase A ----
    bf16x8 afrag[2];
    #pragma unroll
    for (int eh = 0; eh < 2; ++eh) {
        int row = e0 + eh * 16 + ar;
        if (row >= n_edges) row = n_edges - 1;   // safety clamp
        const float* p = efeats + (size_t)row * EF + ak;
        float4 v0 = *(const float4*)p;
        float4 v1 = *(const float4*)(p + 4);
        bf16x8 a;
        a[0] = f2b(v0.x); a[1] = f2b(v0.y); a[2] = f2b(v0.z); a[3] = f2b(v0.w);
        a[4] = f2b(v1.x); a[5] = f2b(v1.y); a[6] = f2b(v1.z); a[7] = f2b(v1.w);
        afrag[eh] = a;
    }
    bf16x8 bfrag[8];
    #pragma unroll
    for (int q = 0; q < 8; ++q) {
        int jt = w * 8 + q;
        bfrag[q] = *(const bf16x8*)(Wet + (size_t)(jt * 16 + ar) * EF + ak);
    }
    f32x4 acc[2][8];
    #pragma unroll
    for (int eh = 0; eh < 2; ++eh)
        #pragma unroll
        for (int q = 0; q < 8; ++q) {
            f32x4 z = {0.f, 0.f, 0.f, 0.f};
            acc[eh][q] = z;
        }
    #pragma unroll
    for (int q = 0; q < 8; ++q) {
        acc[0][q] = __builtin_amdgcn_mfma_f32_16x16x32_bf16(afrag[0], bfrag[q], acc[0][q], 0, 0, 0);
        acc[1][q] = __builtin_amdgcn_mfma_f32_16x16x32_bf16(afrag[1], bfrag[q], acc[1][q], 0, 0, 0);
    }
    // write celu'd bf16 to swizzled LDS
    #pragma unroll
    for (int q = 0; q < 8; ++q) {
        int j = (w * 8 + q) * 16 + ar;
        float bej = be[j];
        int g = j >> 3, go = j & 7;
        #pragma unroll
        for (int eh = 0; eh < 2; ++eh) {
            #pragma unroll
            for (int r4 = 0; r4 < 4; ++r4) {
                int row = eh * 16 + (lane >> 4) * 4 + r4;
                int gs = g ^ (row & 7);
                e512[row * 512 + gs * 8 + go] = f2b(celu_f(acc[eh][q][r4] + bej));
            }
        }
    }
    __syncthreads();

    // ---- Phase B: message + scatter ----
    {
        const int j0 = t * 2;
        const int g = j0 >> 3, go = j0 & 7;
        for (int e = 0; e < 32; ++e) {
            if (e0 + e >= n_edges) break;
            int s_ = s_src[e], d_ = s_dst[e];
            uint hs = *(const uint*)(hb + (size_t)s_ * H + j0);
            uint cs = *(const uint*)(cb + (size_t)s_ * H + j0);
            uint cd = *(const uint*)(cb + (size_t)d_ * H + j0);
            int gs = g ^ (e & 7);
            uint ev = *(const uint*)(&e512[e * 512 + gs * 8 + go]);
            float x0 = fabsf(b2f((ushort)cd) - b2f((ushort)cs)) * (b2f((ushort)hs) * b2f((ushort)ev));
            float x1 = fabsf(b2f((ushort)(cd >> 16)) - b2f((ushort)(cs >> 16))) *
                       (b2f((ushort)(hs >> 16)) * b2f((ushort)(ev >> 16)));
            atomicAdd(&k_acc[(size_t)d_ * H + j0], x0);
            atomicAdd(&k_acc[(size_t)d_ * H + j0 + 1], x1);
        }
    }

    // ---- Phase C: e_out ----
    {
        const int eh = w >> 1, ot = w & 1;
        bf16x8 wfrag[16];
        #pragma unroll
        for (int kt = 0; kt < 16; ++kt) {
            wfrag[kt] = *(const bf16x8*)(Weot + (size_t)(ot * 16 + ar) * H + kt * 32 + ak);
        }
        f32x4 accc = {0.f, 0.f, 0.f, 0.f};
        const int row = eh * 16 + ar;
        #pragma unroll
        for (int kt = 0; kt < 16; ++kt) {
            int g = kt * 4 + (lane >> 4);
            int gs = g ^ (row & 7);
            bf16x8 a = *(const bf16x8*)(&e512[row * 512 + gs * 8]);
            accc = __builtin_amdgcn_mfma_f32_16x16x32_bf16(a, wfrag[kt], accc, 0, 0, 0);
        }
        const int oc = ot * 16 + ar;
        const float bo = beo[oc];
        #pragma unroll
        for (int r4 = 0; r4 < 4; ++r4) {
            int e = e0 + eh * 16 + (lane >> 4) * 4 + r4;
            if (e < n_edges) {
                size_t idx = (size_t)e * EF + oc;
                e_out[idx] = efeats[idx] + celu_f(accc[r4] + bo);
            }
        }
    }
}

// Kernel 3: h_out = hfeats + celu(celu(k@Wn1+bn1)@Wn2+bn2)
__global__ void node_out_kernel(const float* __restrict__ hfeats,
                                const float* __restrict__ k_acc,
                                const float* __restrict__ Wn1, const float* __restrict__ bn1,
                                const float* __restrict__ Wn2, const float* __restrict__ bn2,
                                float* __restrict__ h_out, int n_nodes) {
    __shared__ float kl[8][H];
    __shared__ float tl[8][H];
    const int t = threadIdx.x;
    const int node0 = blockIdx.x * 8;

    for (int i = t; i < 8 * H; i += 256) {
        int n = i / H, j = i % H;
        int node = node0 + n;
        kl[n][j] = (node < n_nodes) ? k_acc[(size_t)node * H + j] : 0.0f;
    }
    __syncthreads();

    for (int jj = 0; jj < 2; ++jj) {
        const int j = jj * 256 + t;
        float acc[8];
        const float bj = bn1[j];
        #pragma unroll
        for (int n = 0; n < 8; ++n) acc[n] = bj;
        for (int kt = 0; kt < H / 8; ++kt) {
            float w[8];
            #pragma unroll
            for (int u = 0; u < 8; ++u) w[u] = Wn1[(size_t)(kt * 8 + u) * H + j];
            #pragma unroll
            for (int n = 0; n < 8; ++n) {
                float a = 0.0f;
                #pragma unroll
                for (int u = 0; u < 8; ++u) a += kl[n][kt * 8 + u] * w[u];
                acc[n] += a;
            }
        }
        #pragma unroll
        for (int n = 0; n < 8; ++n) tl[n][j] = celu_f(acc[n]);
    }
    __syncthreads();

    {
        const int j = t % NF;
        const int nb = t / NF;
        float acc2[4];
        const float bj = bn2[j];
        #pragma unroll
        for (int p = 0; p < 4; ++p) acc2[p] = bj;
        for (int kt = 0; kt < H / 8; ++kt) {
            float w[8];
            #pragma unroll
            for (int u = 0; u < 8; ++u) w[u] = Wn2[(size_t)(kt * 8 + u) * NF + j];
            #pragma unroll
            for (int p = 0; p < 4; ++p) {
                const int n = nb + 2 * p;
                float a = 0.0f;
                #pragma unroll
                for (int u = 0; u < 8; ++u) a += tl[n][kt * 8 + u] * w[u];
                acc2[p] += a;
            }
        }
        #pragma unroll
        for (int p = 0; p < 4; ++p) {
            const int n = nb + 2 * p;
            const int node = node0 + n;
            if (node < n_nodes) {
                h_out[(size_t)node * NF + j] =
                    hfeats[(size_t)node * NF + j] + celu_f(acc2[p]);
            }
        }
    }
}

extern "C" void kernel_launch(void* const* d_in, const int* in_sizes, int n_in,
                              void* d_out, int out_size, void* d_ws, size_t ws_size,
                              hipStream_t stream) {
    const float* hfeats = (const float*)d_in[0];
    const float* cfeats = (const float*)d_in[1];
    const float* efeats = (const float*)d_in[2];
    const int*   src    = (const int*)d_in[3];
    const int*   dst    = (const int*)d_in[4];
    const float* Wn  = (const float*)d_in[5];  const float* bn  = (const float*)d_in[6];
    const float* We  = (const float*)d_in[7];  const float* be  = (const float*)d_in[8];
    const float* Wc  = (const float*)d_in[9];  const float* bc  = (const float*)d_in[10];
    const float* Wn1 = (const float*)d_in[11]; const float* bn1 = (const float*)d_in[12];
    const float* Wn2 = (const float*)d_in[13]; const float* bn2 = (const float*)d_in[14];
    const float* Weo = (const float*)d_in[15]; const float* beo = (const float*)d_in[16];
    const float* Wco = (const float*)d_in[17]; const float* bco = (const float*)d_in[18];

    const int n_nodes = in_sizes[0] / NF;
    const int n_edges = in_sizes[2] / EF;

    // ws layout
    float*  k_buf = (float*)d_ws;                                   // [N,H] f32
    ushort* hb    = (ushort*)(k_buf + (size_t)n_nodes * H);         // [N,H] bf16
    ushort* cb    = hb + (size_t)n_nodes * H;                       // [N,H] bf16
    ushort* Wet   = cb + (size_t)n_nodes * H;                       // [H,EF] bf16
    ushort* Weot  = Wet + (size_t)H * EF;                           // [EF,H] bf16

    float* h_out = (float*)d_out;
    float* c_out = h_out + (size_t)n_nodes * NF;
    float* e_out = c_out + (size_t)n_nodes * CF;

    hipMemsetAsync(k_buf, 0, (size_t)n_nodes * H * sizeof(float), stream);

    prep_kernel<<<(H * EF + 255) / 256, 256, 0, stream>>>(We, Weo, Wet, Weot);

    node_expand_kernel<<<(n_nodes + 15) / 16, 256, 0, stream>>>(
        hfeats, cfeats, Wn, bn, Wc, bc, Wco, bco, hb, cb, c_out, n_nodes);

    edge_kernel<<<(n_edges + 31) / 32, 256, 0, stream>>>(
        efeats, src, dst, Wet, be, Weot, beo, hb, cb, k_buf, e_out, n_edges);

    node_out_kernel<<<(n_nodes + 7) / 8, 256, 0, stream>>>(
        hfeats, k_buf, Wn1, bn1, Wn2, bn2, h_out, n_nodes);
}

// Round 3
// 920.911 us; speedup vs baseline: 2.0166x; 1.6572x over previous
//
#include <hip/hip_runtime.h>
#include <hip/hip_bf16.h>

#define NF 128
#define EF 32
#define CF 3
#define H  512

typedef __attribute__((ext_vector_type(8))) short bf16x8;
typedef __attribute__((ext_vector_type(4))) float f32x4;

__device__ __forceinline__ float celu_f(float x) {
    return x > 0.0f ? x : expm1f(x);
}
__device__ __forceinline__ ushort f2b(float f) {
    union { float f; uint u; } v; v.f = f;
    uint u = v.u + 0x7FFF + ((v.u >> 16) & 1);   // RNE
    return (ushort)(u >> 16);
}
__device__ __forceinline__ float b2f(ushort s) {
    union { uint u; float f; } v; v.u = ((uint)s) << 16; return v.f;
}

// ---------------- sort-by-dst machinery ----------------
__global__ void hist_kernel(const int* __restrict__ dst, int* __restrict__ cnt, int n_edges) {
    int i = blockIdx.x * 256 + threadIdx.x;
    if (i < n_edges) atomicAdd(&cnt[dst[i]], 1);
}

// in-place exclusive scan: cnt[i] <- sum(cnt[0..i-1]); single block, 1024 threads
__global__ void scan_kernel(int* __restrict__ cnt, int n_nodes) {
    __shared__ int part[1024];
    const int t = threadIdx.x;
    const int per = (n_nodes + 1023) / 1024;
    int s = 0;
    for (int i = 0; i < per; ++i) {
        int idx = t * per + i;
        if (idx < n_nodes) s += cnt[idx];
    }
    part[t] = s;
    __syncthreads();
    for (int off = 1; off < 1024; off <<= 1) {
        int v = (t >= off) ? part[t - off] : 0;
        __syncthreads();
        part[t] += v;
        __syncthreads();
    }
    int acc = part[t] - s;   // exclusive prefix of this thread's chunk
    for (int i = 0; i < per; ++i) {
        int idx = t * per + i;
        if (idx < n_nodes) {
            int c = cnt[idx];
            cnt[idx] = acc;
            acc += c;
        }
    }
}

__global__ void scatter_kernel(const int* __restrict__ dst, int* __restrict__ cursor,
                               int* __restrict__ perm, int n_edges) {
    int i = blockIdx.x * 256 + threadIdx.x;
    if (i < n_edges) {
        int pos = atomicAdd(&cursor[dst[i]], 1);
        perm[pos] = i;
    }
}

// prep: Wet[j*EF+k] = bf16(We[k*H+j]);  Weot[o*H+j] = bf16(Weo[j*EF+o])
__global__ void prep_kernel(const float* __restrict__ We, const float* __restrict__ Weo,
                            ushort* __restrict__ Wet, ushort* __restrict__ Weot) {
    int i = blockIdx.x * 256 + threadIdx.x;
    if (i < H * EF) {
        int j = i / EF, k = i % EF;
        Wet[i] = f2b(We[(size_t)k * H + j]);
        int o = i / H, j2 = i % H;
        Weot[i] = f2b(Weo[(size_t)j2 * EF + o]);
    }
}

// Kernel 1: hb = bf16(celu(hfeats@Wn+bn)); cb = bf16(celu(cfeats@Wc+bc));
//           c_out = cfeats + celu(c512@Wco+bco)
__global__ void node_expand_kernel(const float* __restrict__ hfeats,
                                   const float* __restrict__ cfeats,
                                   const float* __restrict__ Wn, const float* __restrict__ bn,
                                   const float* __restrict__ Wc, const float* __restrict__ bc,
                                   const float* __restrict__ Wco, const float* __restrict__ bco,
                                   ushort* __restrict__ hb, ushort* __restrict__ cb,
                                   float* __restrict__ c_out, int n_nodes) {
    __shared__ float hf[16][NF];
    __shared__ float cf[16][4];
    __shared__ float c512[16][H + 4];
    const int t = threadIdx.x;
    const int node0 = blockIdx.x * 16;

    for (int i = t; i < 16 * NF; i += 256) {
        int n = i / NF, k = i % NF;
        int node = node0 + n;
        hf[n][k] = (node < n_nodes) ? hfeats[(size_t)node * NF + k] : 0.0f;
    }
    for (int i = t; i < 16 * CF; i += 256) {
        int n = i / CF, k = i % CF;
        int node = node0 + n;
        cf[n][k] = (node < n_nodes) ? cfeats[(size_t)node * CF + k] : 0.0f;
    }
    __syncthreads();

    for (int jj = 0; jj < 2; ++jj) {
        const int j = jj * 256 + t;
        float acc[16];
        const float bj = bn[j];
        #pragma unroll
        for (int n = 0; n < 16; ++n) acc[n] = bj;
        for (int kt = 0; kt < NF / 8; ++kt) {
            float w[8];
            #pragma unroll
            for (int u = 0; u < 8; ++u) w[u] = Wn[(size_t)(kt * 8 + u) * H + j];
            #pragma unroll
            for (int n = 0; n < 16; ++n) {
                float a = 0.0f;
                #pragma unroll
                for (int u = 0; u < 8; ++u) a += hf[n][kt * 8 + u] * w[u];
                acc[n] += a;
            }
        }
        const float w0 = Wc[j], w1 = Wc[H + j], w2 = Wc[2 * H + j];
        const float bcj = bc[j];
        #pragma unroll
        for (int n = 0; n < 16; ++n) {
            int node = node0 + n;
            float cv = celu_f(bcj + cf[n][0] * w0 + cf[n][1] * w1 + cf[n][2] * w2);
            c512[n][j] = cv;
            if (node < n_nodes) {
                hb[(size_t)node * H + j] = f2b(celu_f(acc[n]));
                cb[(size_t)node * H + j] = f2b(cv);
            }
        }
    }
    __syncthreads();

    if (t < 16 * CF) {
        int n = t / CF, o = t % CF;
        int node = node0 + n;
        if (node < n_nodes) {
            float s = bco[o];
            for (int j2 = 0; j2 < H; ++j2) s += c512[n][j2] * Wco[j2 * CF + o];
            c_out[(size_t)node * CF + o] = cfeats[(size_t)node * CF + o] + celu_f(s);
        }
    }
}

// Kernel 2 (edge, MFMA, dst-sorted): 32 edges/block via perm.
// Phase A: e512 = celu(ef@We+be) via mfma -> swizzled LDS (bf16)
// Phase B: run-accumulated scatter (dst sorted => ~3 flushes per tile)
// Phase C: e_out = efeats + celu(e512@Weo+beo) via mfma
__global__ __launch_bounds__(256) void edge_kernel(
        const float* __restrict__ efeats,
        const int* __restrict__ src, const int* __restrict__ dst,
        const int* __restrict__ perm,
        const ushort* __restrict__ Wet, const float* __restrict__ be,
        const ushort* __restrict__ Weot, const float* __restrict__ beo,
        const ushort* __restrict__ hb, const ushort* __restrict__ cb,
        float* __restrict__ k_acc, float* __restrict__ e_out, int n_edges) {
    __shared__ ushort e512[32 * 512];      // 32 KB, XOR-swizzled in 8-elem groups
    __shared__ int s_perm[32], s_src[32], s_dst[32];
    const int t = threadIdx.x;
    const int lane = t & 63;
    const int w = t >> 6;

    // bijective XCD swizzle: consecutive dst-sorted tiles land on the same XCD
    const int nwg = gridDim.x;
    const int q = nwg >> 3, r = nwg & 7;
    const int xcd = blockIdx.x & 7, sub = blockIdx.x >> 3;
    const int bid = (xcd < r ? xcd * (q + 1) : r * (q + 1) + (xcd - r) * q) + sub;
    const int e0 = bid * 32;

    if (t < 32) {
        int e = e0 + t;
        int pe = (e < n_edges) ? perm[e] : -1;
        s_perm[t] = pe;
        s_src[t] = (pe >= 0) ? src[pe] : 0;
        s_dst[t] = (pe >= 0) ? dst[pe] : -1;
    }
    __syncthreads();

    const int ar = lane & 15;          // row/col within 16-tile
    const int ak = (lane >> 4) * 8;    // k-start for A/B fragments

    // ---- Phase A ----
    bf16x8 afrag[2];
    #pragma unroll
    for (int eh = 0; eh < 2; ++eh) {
        int pe = s_perm[eh * 16 + ar];
        if (pe < 0) pe = 0;
        const float* p = efeats + (size_t)pe * EF + ak;
        float4 v0 = *(const float4*)p;
        float4 v1 = *(const float4*)(p + 4);
        bf16x8 a;
        a[0] = f2b(v0.x); a[1] = f2b(v0.y); a[2] = f2b(v0.z); a[3] = f2b(v0.w);
        a[4] = f2b(v1.x); a[5] = f2b(v1.y); a[6] = f2b(v1.z); a[7] = f2b(v1.w);
        afrag[eh] = a;
    }
    bf16x8 bfrag[8];
    #pragma unroll
    for (int qq = 0; qq < 8; ++qq) {
        int jt = w * 8 + qq;
        bfrag[qq] = *(const bf16x8*)(Wet + (size_t)(jt * 16 + ar) * EF + ak);
    }
    f32x4 acc[2][8];
    #pragma unroll
    for (int eh = 0; eh < 2; ++eh)
        #pragma unroll
        for (int qq = 0; qq < 8; ++qq) {
            f32x4 z = {0.f, 0.f, 0.f, 0.f};
            acc[eh][qq] = z;
        }
    #pragma unroll
    for (int qq = 0; qq < 8; ++qq) {
        acc[0][qq] = __builtin_amdgcn_mfma_f32_16x16x32_bf16(afrag[0], bfrag[qq], acc[0][qq], 0, 0, 0);
        acc[1][qq] = __builtin_amdgcn_mfma_f32_16x16x32_bf16(afrag[1], bfrag[qq], acc[1][qq], 0, 0, 0);
    }
    #pragma unroll
    for (int qq = 0; qq < 8; ++qq) {
        int j = (w * 8 + qq) * 16 + ar;
        float bej = be[j];
        int g = j >> 3, go = j & 7;
        #pragma unroll
        for (int eh = 0; eh < 2; ++eh) {
            #pragma unroll
            for (int r4 = 0; r4 < 4; ++r4) {
                int row = eh * 16 + (lane >> 4) * 4 + r4;
                int gs = g ^ (row & 7);
                e512[row * 512 + gs * 8 + go] = f2b(celu_f(acc[eh][qq][r4] + bej));
            }
        }
    }
    __syncthreads();

    // ---- Phase B: run-accumulated message + scatter ----
    {
        const int j0 = t * 2;
        const int g = j0 >> 3, go = j0 & 7;
        float a0 = 0.f, a1 = 0.f;
        int cur = -1;
        uint cdv = 0;
        for (int e = 0; e < 32; ++e) {
            int d = s_dst[e];
            if (d != cur) {
                if (cur >= 0) {
                    atomicAdd(&k_acc[(size_t)cur * H + j0], a0);
                    atomicAdd(&k_acc[(size_t)cur * H + j0 + 1], a1);
                }
                a0 = 0.f; a1 = 0.f;
                cur = d;
                if (d >= 0) cdv = *(const uint*)(cb + (size_t)d * H + j0);
            }
            if (d < 0) continue;
            int s_ = s_src[e];
            uint hs = *(const uint*)(hb + (size_t)s_ * H + j0);
            uint cs = *(const uint*)(cb + (size_t)s_ * H + j0);
            int gs = g ^ (e & 7);
            uint ev = *(const uint*)(&e512[e * 512 + gs * 8 + go]);
            a0 += fabsf(b2f((ushort)cdv) - b2f((ushort)cs)) * (b2f((ushort)hs) * b2f((ushort)ev));
            a1 += fabsf(b2f((ushort)(cdv >> 16)) - b2f((ushort)(cs >> 16))) *
                  (b2f((ushort)(hs >> 16)) * b2f((ushort)(ev >> 16)));
        }
        if (cur >= 0) {
            atomicAdd(&k_acc[(size_t)cur * H + j0], a0);
            atomicAdd(&k_acc[(size_t)cur * H + j0 + 1], a1);
        }
    }

    // ---- Phase C: e_out ----
    {
        const int eh = w >> 1, ot = w & 1;
        bf16x8 wfrag[16];
        #pragma unroll
        for (int kt = 0; kt < 16; ++kt) {
            wfrag[kt] = *(const bf16x8*)(Weot + (size_t)(ot * 16 + ar) * H + kt * 32 + ak);
        }
        f32x4 accc = {0.f, 0.f, 0.f, 0.f};
        const int row = eh * 16 + ar;
        #pragma unroll
        for (int kt = 0; kt < 16; ++kt) {
            int g = kt * 4 + (lane >> 4);
            int gs = g ^ (row & 7);
            bf16x8 a = *(const bf16x8*)(&e512[row * 512 + gs * 8]);
            accc = __builtin_amdgcn_mfma_f32_16x16x32_bf16(a, wfrag[kt], accc, 0, 0, 0);
        }
        const int oc = ot * 16 + ar;
        const float bo = beo[oc];
        #pragma unroll
        for (int r4 = 0; r4 < 4; ++r4) {
            int pe = s_perm[eh * 16 + (lane >> 4) * 4 + r4];
            if (pe >= 0) {
                size_t idx = (size_t)pe * EF + oc;
                e_out[idx] = efeats[idx] + celu_f(accc[r4] + bo);
            }
        }
    }
}

// Kernel 3: h_out = hfeats + celu(celu(k@Wn1+bn1)@Wn2+bn2)
__global__ void node_out_kernel(const float* __restrict__ hfeats,
                                const float* __restrict__ k_acc,
                                const float* __restrict__ Wn1, const float* __restrict__ bn1,
                                const float* __restrict__ Wn2, const float* __restrict__ bn2,
                                float* __restrict__ h_out, int n_nodes) {
    __shared__ float kl[8][H];
    __shared__ float tl[8][H];
    const int t = threadIdx.x;
    const int node0 = blockIdx.x * 8;

    for (int i = t; i < 8 * H; i += 256) {
        int n = i / H, j = i % H;
        int node = node0 + n;
        kl[n][j] = (node < n_nodes) ? k_acc[(size_t)node * H + j] : 0.0f;
    }
    __syncthreads();

    for (int jj = 0; jj < 2; ++jj) {
        const int j = jj * 256 + t;
        float acc[8];
        const float bj = bn1[j];
        #pragma unroll
        for (int n = 0; n < 8; ++n) acc[n] = bj;
        for (int kt = 0; kt < H / 8; ++kt) {
            float w[8];
            #pragma unroll
            for (int u = 0; u < 8; ++u) w[u] = Wn1[(size_t)(kt * 8 + u) * H + j];
            #pragma unroll
            for (int n = 0; n < 8; ++n) {
                float a = 0.0f;
                #pragma unroll
                for (int u = 0; u < 8; ++u) a += kl[n][kt * 8 + u] * w[u];
                acc[n] += a;
            }
        }
        #pragma unroll
        for (int n = 0; n < 8; ++n) tl[n][j] = celu_f(acc[n]);
    }
    __syncthreads();

    {
        const int j = t % NF;
        const int nb = t / NF;
        float acc2[4];
        const float bj = bn2[j];
        #pragma unroll
        for (int p = 0; p < 4; ++p) acc2[p] = bj;
        for (int kt = 0; kt < H / 8; ++kt) {
            float w[8];
            #pragma unroll
            for (int u = 0; u < 8; ++u) w[u] = Wn2[(size_t)(kt * 8 + u) * NF + j];
            #pragma unroll
            for (int p = 0; p < 4; ++p) {
                const int n = nb + 2 * p;
                float a = 0.0f;
                #pragma unroll
                for (int u = 0; u < 8; ++u) a += tl[n][kt * 8 + u] * w[u];
                acc2[p] += a;
            }
        }
        #pragma unroll
        for (int p = 0; p < 4; ++p) {
            const int n = nb + 2 * p;
            const int node = node0 + n;
            if (node < n_nodes) {
                h_out[(size_t)node * NF + j] =
                    hfeats[(size_t)node * NF + j] + celu_f(acc2[p]);
            }
        }
    }
}

extern "C" void kernel_launch(void* const* d_in, const int* in_sizes, int n_in,
                              void* d_out, int out_size, void* d_ws, size_t ws_size,
                              hipStream_t stream) {
    const float* hfeats = (const float*)d_in[0];
    const float* cfeats = (const float*)d_in[1];
    const float* efeats = (const float*)d_in[2];
    const int*   src    = (const int*)d_in[3];
    const int*   dst    = (const int*)d_in[4];
    const float* Wn  = (const float*)d_in[5];  const float* bn  = (const float*)d_in[6];
    const float* We  = (const float*)d_in[7];  const float* be  = (const float*)d_in[8];
    const float* Wc  = (const float*)d_in[9];  const float* bc  = (const float*)d_in[10];
    const float* Wn1 = (const float*)d_in[11]; const float* bn1 = (const float*)d_in[12];
    const float* Wn2 = (const float*)d_in[13]; const float* bn2 = (const float*)d_in[14];
    const float* Weo = (const float*)d_in[15]; const float* beo = (const float*)d_in[16];
    const float* Wco = (const float*)d_in[17]; const float* bco = (const float*)d_in[18];

    const int n_nodes = in_sizes[0] / NF;
    const int n_edges = in_sizes[2] / EF;

    // ws layout
    float*  k_buf = (float*)d_ws;                                   // [N,H] f32
    ushort* hb    = (ushort*)(k_buf + (size_t)n_nodes * H);         // [N,H] bf16
    ushort* cb    = hb + (size_t)n_nodes * H;                       // [N,H] bf16
    ushort* Wet   = cb + (size_t)n_nodes * H;                       // [H,EF] bf16
    ushort* Weot  = Wet + (size_t)H * EF;                           // [EF,H] bf16
    int*    cnt   = (int*)(Weot + (size_t)H * EF);                  // [N] int (becomes cursor)
    int*    perm  = cnt + n_nodes;                                  // [E] int

    float* h_out = (float*)d_out;
    float* c_out = h_out + (size_t)n_nodes * NF;
    float* e_out = c_out + (size_t)n_nodes * CF;

    hipMemsetAsync(k_buf, 0, (size_t)n_nodes * H * sizeof(float), stream);
    hipMemsetAsync(cnt, 0, (size_t)n_nodes * sizeof(int), stream);

    prep_kernel<<<(H * EF + 255) / 256, 256, 0, stream>>>(We, Weo, Wet, Weot);
    hist_kernel<<<(n_edges + 255) / 256, 256, 0, stream>>>(dst, cnt, n_edges);
    scan_kernel<<<1, 1024, 0, stream>>>(cnt, n_nodes);
    scatter_kernel<<<(n_edges + 255) / 256, 256, 0, stream>>>(dst, cnt, perm, n_edges);

    node_expand_kernel<<<(n_nodes + 15) / 16, 256, 0, stream>>>(
        hfeats, cfeats, Wn, bn, Wc, bc, Wco, bco, hb, cb, c_out, n_nodes);

    edge_kernel<<<(n_edges + 31) / 32, 256, 0, stream>>>(
        efeats, src, dst, perm, Wet, be, Weot, beo, hb, cb, k_buf, e_out, n_edges);

    node_out_kernel<<<(n_nodes + 7) / 8, 256, 0, stream>>>(
        hfeats, k_buf, Wn1, bn1, Wn2, bn2, h_out, n_nodes);
}

// Round 4
// 644.169 us; speedup vs baseline: 2.8829x; 1.4296x over previous
//
#include <hip/hip_runtime.h>
#include <hip/hip_bf16.h>

#define NF 128
#define EF 32
#define CF 3
#define H  512

typedef __attribute__((ext_vector_type(8))) short bf16x8;
typedef __attribute__((ext_vector_type(4))) float f32x4;

__device__ __forceinline__ float celu_f(float x) {
    return x > 0.0f ? x : expm1f(x);
}
__device__ __forceinline__ ushort f2b(float f) {
    union { float f; uint u; } v; v.f = f;
    uint u = v.u + 0x7FFF + ((v.u >> 16) & 1);   // RNE
    return (ushort)(u >> 16);
}
__device__ __forceinline__ float b2f(ushort s) {
    union { uint u; float f; } v; v.u = ((uint)s) << 16; return v.f;
}

// ---------------- sort-by-dst machinery ----------------
__global__ void hist_kernel(const int* __restrict__ dst, int* __restrict__ cnt, int n_edges) {
    int i = blockIdx.x * 256 + threadIdx.x;
    if (i < n_edges) atomicAdd(&cnt[dst[i]], 1);
}

__global__ void scan_kernel(int* __restrict__ cnt, int n_nodes) {
    __shared__ int part[1024];
    const int t = threadIdx.x;
    const int per = (n_nodes + 1023) / 1024;
    int s = 0;
    for (int i = 0; i < per; ++i) {
        int idx = t * per + i;
        if (idx < n_nodes) s += cnt[idx];
    }
    part[t] = s;
    __syncthreads();
    for (int off = 1; off < 1024; off <<= 1) {
        int v = (t >= off) ? part[t - off] : 0;
        __syncthreads();
        part[t] += v;
        __syncthreads();
    }
    int acc = part[t] - s;
    for (int i = 0; i < per; ++i) {
        int idx = t * per + i;
        if (idx < n_nodes) {
            int c = cnt[idx];
            cnt[idx] = acc;
            acc += c;
        }
    }
}

__global__ void scatter_kernel(const int* __restrict__ dst, int* __restrict__ cursor,
                               int* __restrict__ perm, int n_edges) {
    int i = blockIdx.x * 256 + threadIdx.x;
    if (i < n_edges) {
        int pos = atomicAdd(&cursor[dst[i]], 1);
        perm[pos] = i;
    }
}

// prep: bf16-transposed weights.
// Wet[j*EF+k]   = We[k*H+j]      (j<512,k<32)
// Weot[o*H+j]   = Weo[j*EF+o]    (o<32,j<512)
// Wnt[o*NF+k]   = Wn[k*H+o]      (o<512,k<128)
// Wn1t[o*H+k]   = Wn1[k*H+o]     (o<512,k<512)
// Wn2t[o*H+k]   = Wn2[k*NF+o]    (o<128,k<512)
__global__ void prep_kernel(const float* __restrict__ We, const float* __restrict__ Weo,
                            const float* __restrict__ Wn, const float* __restrict__ Wn1,
                            const float* __restrict__ Wn2,
                            ushort* __restrict__ Wet, ushort* __restrict__ Weot,
                            ushort* __restrict__ Wnt, ushort* __restrict__ Wn1t,
                            ushort* __restrict__ Wn2t) {
    int i = blockIdx.x * 256 + threadIdx.x;
    if (i < H * EF) {
        int j = i / EF, k = i % EF;
        Wet[i] = f2b(We[(size_t)k * H + j]);
        int o = i / H, j2 = i % H;
        Weot[i] = f2b(Weo[(size_t)j2 * EF + o]);
    }
    if (i < H * NF) {
        int o = i >> 7, k = i & 127;
        Wnt[i] = f2b(Wn[(size_t)k * H + o]);
        int o2 = i >> 9, k2 = i & 511;
        Wn2t[i] = f2b(Wn2[(size_t)k2 * NF + o2]);
    }
    if (i < H * H) {
        int o = i >> 9, k = i & 511;
        Wn1t[i] = f2b(Wn1[(size_t)k * H + o]);
    }
}

// Kernel 1 (MFMA): hb = bf16(celu(hfeats@Wn+bn)) ; cb = bf16(celu(cfeats@Wc+bc))
// 32 nodes/block, 4 waves.
__global__ __launch_bounds__(256) void node_expand_kernel(
        const float* __restrict__ hfeats, const float* __restrict__ cfeats,
        const ushort* __restrict__ Wnt, const float* __restrict__ bn,
        const float* __restrict__ Wc, const float* __restrict__ bc,
        ushort* __restrict__ hb, ushort* __restrict__ cb, int n_nodes) {
    __shared__ ushort hf[32 * NF];     // 8 KB, granule-swizzled
    __shared__ float cf[32][4];
    const int t = threadIdx.x;
    const int lane = t & 63;
    const int w = t >> 6;
    const int node0 = blockIdx.x * 32;

    // stage hfeats -> bf16 LDS (16B granules, swizzle g^=(row&7))
    for (int i = t; i < 32 * 16; i += 256) {
        int row = i >> 4, g = i & 15;
        int node = node0 + row; if (node >= n_nodes) node = n_nodes - 1;
        const float* p = hfeats + (size_t)node * NF + g * 8;
        float4 v0 = *(const float4*)p;
        float4 v1 = *(const float4*)(p + 4);
        bf16x8 a;
        a[0] = f2b(v0.x); a[1] = f2b(v0.y); a[2] = f2b(v0.z); a[3] = f2b(v0.w);
        a[4] = f2b(v1.x); a[5] = f2b(v1.y); a[6] = f2b(v1.z); a[7] = f2b(v1.w);
        ((bf16x8*)hf)[row * 16 + (g ^ (row & 7))] = a;
    }
    for (int i = t; i < 32 * CF; i += 256) {
        int n = i / CF, k = i % CF;
        int node = node0 + n; if (node >= n_nodes) node = n_nodes - 1;
        cf[n][k] = cfeats[(size_t)node * CF + k];
    }
    __syncthreads();

    const int ar = lane & 15;
    const int ak = (lane >> 4) * 8;

    f32x4 acc[2][8];
    #pragma unroll
    for (int eh = 0; eh < 2; ++eh)
        #pragma unroll
        for (int q = 0; q < 8; ++q) { f32x4 z = {0.f,0.f,0.f,0.f}; acc[eh][q] = z; }

    for (int kstep = 0; kstep < NF / 32; ++kstep) {
        bf16x8 afrag[2];
        #pragma unroll
        for (int eh = 0; eh < 2; ++eh) {
            int r = eh * 16 + ar;
            int g = kstep * 4 + (lane >> 4);
            afrag[eh] = ((const bf16x8*)hf)[r * 16 + (g ^ (r & 7))];
        }
        #pragma unroll
        for (int q = 0; q < 8; ++q) {
            bf16x8 bfrag = *(const bf16x8*)(Wnt + (size_t)((w * 8 + q) * 16 + ar) * NF + kstep * 32 + ak);
            acc[0][q] = __builtin_amdgcn_mfma_f32_16x16x32_bf16(afrag[0], bfrag, acc[0][q], 0, 0, 0);
            acc[1][q] = __builtin_amdgcn_mfma_f32_16x16x32_bf16(afrag[1], bfrag, acc[1][q], 0, 0, 0);
        }
    }
    #pragma unroll
    for (int q = 0; q < 8; ++q) {
        int col = (w * 8 + q) * 16 + ar;
        float bj = bn[col];
        #pragma unroll
        for (int eh = 0; eh < 2; ++eh) {
            #pragma unroll
            for (int r4 = 0; r4 < 4; ++r4) {
                int row = eh * 16 + (lane >> 4) * 4 + r4;
                int node = node0 + row;
                if (node < n_nodes)
                    hb[(size_t)node * H + col] = f2b(celu_f(acc[eh][q][r4] + bj));
            }
        }
    }

    // coord expansion: cb = bf16(celu(cf@Wc+bc)), coalesced over j
    for (int i = t; i < 32 * H; i += 256) {
        int n = i >> 9, j = i & 511;
        int node = node0 + n;
        if (node < n_nodes) {
            float cv = celu_f(bc[j] + cf[n][0] * Wc[j] + cf[n][1] * Wc[H + j] + cf[n][2] * Wc[2 * H + j]);
            cb[(size_t)node * H + j] = f2b(cv);
        }
    }
}

// c_out kernel: c_out = cfeats + celu(c512@Wco+bco); one wave per node
__global__ __launch_bounds__(256) void c_out_kernel(
        const float* __restrict__ cfeats, const ushort* __restrict__ cb,
        const float* __restrict__ Wco, const float* __restrict__ bco,
        float* __restrict__ c_out, int n_nodes) {
    const int t = threadIdx.x;
    const int lane = t & 63;
    const int w = t >> 6;
    const int node = blockIdx.x * 4 + w;
    if (node >= n_nodes) return;
    float a0 = 0.f, a1 = 0.f, a2 = 0.f;
    bf16x8 v = ((const bf16x8*)(cb + (size_t)node * H))[lane];
    #pragma unroll
    for (int u = 0; u < 8; ++u) {
        int j = lane * 8 + u;
        float cv = b2f((ushort)v[u]);
        a0 += cv * Wco[j * CF + 0];
        a1 += cv * Wco[j * CF + 1];
        a2 += cv * Wco[j * CF + 2];
    }
    #pragma unroll
    for (int m = 32; m >= 1; m >>= 1) {
        a0 += __shfl_xor(a0, m);
        a1 += __shfl_xor(a1, m);
        a2 += __shfl_xor(a2, m);
    }
    if (lane < 3) {
        float s = (lane == 0) ? a0 : (lane == 1) ? a1 : a2;
        c_out[(size_t)node * CF + lane] = cfeats[(size_t)node * CF + lane] + celu_f(bco[lane] + s);
    }
}

// Kernel 2 (edge, MFMA, dst-sorted): unchanged from R3
__global__ __launch_bounds__(256) void edge_kernel(
        const float* __restrict__ efeats,
        const int* __restrict__ src, const int* __restrict__ dst,
        const int* __restrict__ perm,
        const ushort* __restrict__ Wet, const float* __restrict__ be,
        const ushort* __restrict__ Weot, const float* __restrict__ beo,
        const ushort* __restrict__ hb, const ushort* __restrict__ cb,
        float* __restrict__ k_acc, float* __restrict__ e_out, int n_edges) {
    __shared__ ushort e512[32 * 512];
    __shared__ int s_perm[32], s_src[32], s_dst[32];
    const int t = threadIdx.x;
    const int lane = t & 63;
    const int w = t >> 6;

    const int nwg = gridDim.x;
    const int q = nwg >> 3, r = nwg & 7;
    const int xcd = blockIdx.x & 7, sub = blockIdx.x >> 3;
    const int bid = (xcd < r ? xcd * (q + 1) : r * (q + 1) + (xcd - r) * q) + sub;
    const int e0 = bid * 32;

    if (t < 32) {
        int e = e0 + t;
        int pe = (e < n_edges) ? perm[e] : -1;
        s_perm[t] = pe;
        s_src[t] = (pe >= 0) ? src[pe] : 0;
        s_dst[t] = (pe >= 0) ? dst[pe] : -1;
    }
    __syncthreads();

    const int ar = lane & 15;
    const int ak = (lane >> 4) * 8;

    bf16x8 afrag[2];
    #pragma unroll
    for (int eh = 0; eh < 2; ++eh) {
        int pe = s_perm[eh * 16 + ar];
        if (pe < 0) pe = 0;
        const float* p = efeats + (size_t)pe * EF + ak;
        float4 v0 = *(const float4*)p;
        float4 v1 = *(const float4*)(p + 4);
        bf16x8 a;
        a[0] = f2b(v0.x); a[1] = f2b(v0.y); a[2] = f2b(v0.z); a[3] = f2b(v0.w);
        a[4] = f2b(v1.x); a[5] = f2b(v1.y); a[6] = f2b(v1.z); a[7] = f2b(v1.w);
        afrag[eh] = a;
    }
    bf16x8 bfrag[8];
    #pragma unroll
    for (int qq = 0; qq < 8; ++qq) {
        int jt = w * 8 + qq;
        bfrag[qq] = *(const bf16x8*)(Wet + (size_t)(jt * 16 + ar) * EF + ak);
    }
    f32x4 acc[2][8];
    #pragma unroll
    for (int eh = 0; eh < 2; ++eh)
        #pragma unroll
        for (int qq = 0; qq < 8; ++qq) { f32x4 z = {0.f,0.f,0.f,0.f}; acc[eh][qq] = z; }
    #pragma unroll
    for (int qq = 0; qq < 8; ++qq) {
        acc[0][qq] = __builtin_amdgcn_mfma_f32_16x16x32_bf16(afrag[0], bfrag[qq], acc[0][qq], 0, 0, 0);
        acc[1][qq] = __builtin_amdgcn_mfma_f32_16x16x32_bf16(afrag[1], bfrag[qq], acc[1][qq], 0, 0, 0);
    }
    #pragma unroll
    for (int qq = 0; qq < 8; ++qq) {
        int j = (w * 8 + qq) * 16 + ar;
        float bej = be[j];
        int g = j >> 3, go = j & 7;
        #pragma unroll
        for (int eh = 0; eh < 2; ++eh) {
            #pragma unroll
            for (int r4 = 0; r4 < 4; ++r4) {
                int row = eh * 16 + (lane >> 4) * 4 + r4;
                int gs = g ^ (row & 7);
                e512[row * 512 + gs * 8 + go] = f2b(celu_f(acc[eh][qq][r4] + bej));
            }
        }
    }
    __syncthreads();

    {
        const int j0 = t * 2;
        const int g = j0 >> 3, go = j0 & 7;
        float a0 = 0.f, a1 = 0.f;
        int cur = -1;
        uint cdv = 0;
        for (int e = 0; e < 32; ++e) {
            int d = s_dst[e];
            if (d != cur) {
                if (cur >= 0) {
                    atomicAdd(&k_acc[(size_t)cur * H + j0], a0);
                    atomicAdd(&k_acc[(size_t)cur * H + j0 + 1], a1);
                }
                a0 = 0.f; a1 = 0.f;
                cur = d;
                if (d >= 0) cdv = *(const uint*)(cb + (size_t)d * H + j0);
            }
            if (d < 0) continue;
            int s_ = s_src[e];
            uint hs = *(const uint*)(hb + (size_t)s_ * H + j0);
            uint cs = *(const uint*)(cb + (size_t)s_ * H + j0);
            int gs = g ^ (e & 7);
            uint ev = *(const uint*)(&e512[e * 512 + gs * 8 + go]);
            a0 += fabsf(b2f((ushort)cdv) - b2f((ushort)cs)) * (b2f((ushort)hs) * b2f((ushort)ev));
            a1 += fabsf(b2f((ushort)(cdv >> 16)) - b2f((ushort)(cs >> 16))) *
                  (b2f((ushort)(hs >> 16)) * b2f((ushort)(ev >> 16)));
        }
        if (cur >= 0) {
            atomicAdd(&k_acc[(size_t)cur * H + j0], a0);
            atomicAdd(&k_acc[(size_t)cur * H + j0 + 1], a1);
        }
    }

    {
        const int eh = w >> 1, ot = w & 1;
        bf16x8 wfrag[16];
        #pragma unroll
        for (int kt = 0; kt < 16; ++kt) {
            wfrag[kt] = *(const bf16x8*)(Weot + (size_t)(ot * 16 + ar) * H + kt * 32 + ak);
        }
        f32x4 accc = {0.f, 0.f, 0.f, 0.f};
        const int row = eh * 16 + ar;
        #pragma unroll
        for (int kt = 0; kt < 16; ++kt) {
            int g = kt * 4 + (lane >> 4);
            int gs = g ^ (row & 7);
            bf16x8 a = *(const bf16x8*)(&e512[row * 512 + gs * 8]);
            accc = __builtin_amdgcn_mfma_f32_16x16x32_bf16(a, wfrag[kt], accc, 0, 0, 0);
        }
        const int oc = ot * 16 + ar;
        const float bo = beo[oc];
        #pragma unroll
        for (int r4 = 0; r4 < 4; ++r4) {
            int pe = s_perm[eh * 16 + (lane >> 4) * 4 + r4];
            if (pe >= 0) {
                size_t idx = (size_t)pe * EF + oc;
                e_out[idx] = efeats[idx] + celu_f(accc[r4] + bo);
            }
        }
    }
}

// Kernel 3 (MFMA): h_out = hfeats + celu(celu(k@Wn1+bn1)@Wn2+bn2)
// 32 nodes/block, 4 waves, single 32KB LDS buffer reused (k-tile then t-tile)
__global__ __launch_bounds__(256) void node_out_kernel(
        const float* __restrict__ hfeats, const float* __restrict__ k_acc,
        const ushort* __restrict__ Wn1t, const float* __restrict__ bn1,
        const ushort* __restrict__ Wn2t, const float* __restrict__ bn2,
        float* __restrict__ h_out, int n_nodes) {
    __shared__ ushort kt_s[32 * H];   // 32 KB, granule-swizzled; reused for t-tile
    const int t = threadIdx.x;
    const int lane = t & 63;
    const int w = t >> 6;
    const int node0 = blockIdx.x * 32;

    // stage k tile -> bf16 LDS (64 granules/row, swizzle g^=(row&7))
    for (int i = t; i < 32 * 64; i += 256) {
        int row = i >> 6, g = i & 63;
        int node = node0 + row; if (node >= n_nodes) node = n_nodes - 1;
        const float* p = k_acc + (size_t)node * H + g * 8;
        float4 v0 = *(const float4*)p;
        float4 v1 = *(const float4*)(p + 4);
        bf16x8 a;
        a[0] = f2b(v0.x); a[1] = f2b(v0.y); a[2] = f2b(v0.z); a[3] = f2b(v0.w);
        a[4] = f2b(v1.x); a[5] = f2b(v1.y); a[6] = f2b(v1.z); a[7] = f2b(v1.w);
        ((bf16x8*)kt_s)[row * 64 + (g ^ (row & 7))] = a;
    }
    __syncthreads();

    const int ar = lane & 15;
    const int ak = (lane >> 4) * 8;

    // GEMM1: t = celu(k @ Wn1 + bn1); wave w -> cols w*128..w*128+127
    f32x4 acc[2][8];
    #pragma unroll
    for (int eh = 0; eh < 2; ++eh)
        #pragma unroll
        for (int q = 0; q < 8; ++q) { f32x4 z = {0.f,0.f,0.f,0.f}; acc[eh][q] = z; }

    for (int kstep = 0; kstep < H / 32; ++kstep) {
        bf16x8 afrag[2];
        #pragma unroll
        for (int eh = 0; eh < 2; ++eh) {
            int r = eh * 16 + ar;
            int g = kstep * 4 + (lane >> 4);
            afrag[eh] = ((const bf16x8*)kt_s)[r * 64 + (g ^ (r & 7))];
        }
        #pragma unroll
        for (int q = 0; q < 8; ++q) {
            bf16x8 bfrag = *(const bf16x8*)(Wn1t + (size_t)((w * 8 + q) * 16 + ar) * H + kstep * 32 + ak);
            acc[0][q] = __builtin_amdgcn_mfma_f32_16x16x32_bf16(afrag[0], bfrag, acc[0][q], 0, 0, 0);
            acc[1][q] = __builtin_amdgcn_mfma_f32_16x16x32_bf16(afrag[1], bfrag, acc[1][q], 0, 0, 0);
        }
    }
    __syncthreads();   // everyone done reading k-tile

    // write t-tile (celu) into same LDS, swizzled
    #pragma unroll
    for (int q = 0; q < 8; ++q) {
        int col = (w * 8 + q) * 16 + ar;
        float bj = bn1[col];
        int g = col >> 3, go = col & 7;
        #pragma unroll
        for (int eh = 0; eh < 2; ++eh) {
            #pragma unroll
            for (int r4 = 0; r4 < 4; ++r4) {
                int row = eh * 16 + (lane >> 4) * 4 + r4;
                int gs = g ^ (row & 7);
                kt_s[row * 512 + gs * 8 + go] = f2b(celu_f(acc[eh][q][r4] + bj));
            }
        }
    }
    __syncthreads();

    // GEMM2: h = celu(t @ Wn2 + bn2) + hfeats; wave w -> cols w*32..w*32+31
    f32x4 acc2[2][2];
    #pragma unroll
    for (int eh = 0; eh < 2; ++eh)
        #pragma unroll
        for (int ct = 0; ct < 2; ++ct) { f32x4 z = {0.f,0.f,0.f,0.f}; acc2[eh][ct] = z; }

    for (int kstep = 0; kstep < H / 32; ++kstep) {
        bf16x8 afrag[2];
        #pragma unroll
        for (int eh = 0; eh < 2; ++eh) {
            int r = eh * 16 + ar;
            int g = kstep * 4 + (lane >> 4);
            afrag[eh] = ((const bf16x8*)kt_s)[r * 64 + (g ^ (r & 7))];
        }
        #pragma unroll
        for (int ct = 0; ct < 2; ++ct) {
            bf16x8 bfrag = *(const bf16x8*)(Wn2t + (size_t)((w * 2 + ct) * 16 + ar) * H + kstep * 32 + ak);
            acc2[0][ct] = __builtin_amdgcn_mfma_f32_16x16x32_bf16(afrag[0], bfrag, acc2[0][ct], 0, 0, 0);
            acc2[1][ct] = __builtin_amdgcn_mfma_f32_16x16x32_bf16(afrag[1], bfrag, acc2[1][ct], 0, 0, 0);
        }
    }
    #pragma unroll
    for (int ct = 0; ct < 2; ++ct) {
        int col = (w * 2 + ct) * 16 + ar;
        float bj = bn2[col];
        #pragma unroll
        for (int eh = 0; eh < 2; ++eh) {
            #pragma unroll
            for (int r4 = 0; r4 < 4; ++r4) {
                int row = eh * 16 + (lane >> 4) * 4 + r4;
                int node = node0 + row;
                if (node < n_nodes) {
                    size_t idx = (size_t)node * NF + col;
                    h_out[idx] = hfeats[idx] + celu_f(acc2[eh][ct][r4] + bj);
                }
            }
        }
    }
}

extern "C" void kernel_launch(void* const* d_in, const int* in_sizes, int n_in,
                              void* d_out, int out_size, void* d_ws, size_t ws_size,
                              hipStream_t stream) {
    const float* hfeats = (const float*)d_in[0];
    const float* cfeats = (const float*)d_in[1];
    const float* efeats = (const float*)d_in[2];
    const int*   src    = (const int*)d_in[3];
    const int*   dst    = (const int*)d_in[4];
    const float* Wn  = (const float*)d_in[5];  const float* bn  = (const float*)d_in[6];
    const float* We  = (const float*)d_in[7];  const float* be  = (const float*)d_in[8];
    const float* Wc  = (const float*)d_in[9];  const float* bc  = (const float*)d_in[10];
    const float* Wn1 = (const float*)d_in[11]; const float* bn1 = (const float*)d_in[12];
    const float* Wn2 = (const float*)d_in[13]; const float* bn2 = (const float*)d_in[14];
    const float* Weo = (const float*)d_in[15]; const float* beo = (const float*)d_in[16];
    const float* Wco = (const float*)d_in[17]; const float* bco = (const float*)d_in[18];

    const int n_nodes = in_sizes[0] / NF;
    const int n_edges = in_sizes[2] / EF;

    // ws layout
    float*  k_buf = (float*)d_ws;                                   // [N,H] f32
    ushort* hb    = (ushort*)(k_buf + (size_t)n_nodes * H);         // [N,H] bf16
    ushort* cb    = hb + (size_t)n_nodes * H;                       // [N,H] bf16
    ushort* Wet   = cb + (size_t)n_nodes * H;                       // [H,EF]
    ushort* Weot  = Wet + (size_t)H * EF;                           // [EF,H]
    ushort* Wnt   = Weot + (size_t)H * EF;                          // [H,NF]
    ushort* Wn1t  = Wnt + (size_t)H * NF;                           // [H,H]
    ushort* Wn2t  = Wn1t + (size_t)H * H;                           // [NF,H]
    int*    cnt   = (int*)(Wn2t + (size_t)NF * H);                  // [N]
    int*    perm  = cnt + n_nodes;                                  // [E]

    float* h_out = (float*)d_out;
    float* c_out = h_out + (size_t)n_nodes * NF;
    float* e_out = c_out + (size_t)n_nodes * CF;

    hipMemsetAsync(k_buf, 0, (size_t)n_nodes * H * sizeof(float), stream);
    hipMemsetAsync(cnt, 0, (size_t)n_nodes * sizeof(int), stream);

    prep_kernel<<<(H * H + 255) / 256, 256, 0, stream>>>(
        We, Weo, Wn, Wn1, Wn2, Wet, Weot, Wnt, Wn1t, Wn2t);
    hist_kernel<<<(n_edges + 255) / 256, 256, 0, stream>>>(dst, cnt, n_edges);
    scan_kernel<<<1, 1024, 0, stream>>>(cnt, n_nodes);
    scatter_kernel<<<(n_edges + 255) / 256, 256, 0, stream>>>(dst, cnt, perm, n_edges);

    node_expand_kernel<<<(n_nodes + 31) / 32, 256, 0, stream>>>(
        hfeats, cfeats, Wnt, bn, Wc, bc, hb, cb, n_nodes);

    c_out_kernel<<<(n_nodes + 3) / 4, 256, 0, stream>>>(
        cfeats, cb, Wco, bco, c_out, n_nodes);

    edge_kernel<<<(n_edges + 31) / 32, 256, 0, stream>>>(
        efeats, src, dst, perm, Wet, be, Weot, beo, hb, cb, k_buf, e_out, n_edges);

    node_out_kernel<<<(n_nodes + 31) / 32, 256, 0, stream>>>(
        hfeats, k_buf, Wn1t, bn1, Wn2t, bn2, h_out, n_nodes);
}